// Round 18
// baseline (189.147 us; speedup 1.0000x reference)
//
#include <hip/hip_runtime.h>
#include <hip/hip_bf16.h>

#define DIM 256
#define HW  1024  // 32*32

typedef __attribute__((ext_vector_type(8))) short short8;
typedef __attribute__((ext_vector_type(4))) float floatx4;
typedef __attribute__((ext_vector_type(16))) float floatx16;
typedef __attribute__((address_space(1))) const unsigned int g_u32;
typedef __attribute__((address_space(3))) unsigned int l_u32;

// softmax scale folded into Q at conv epilogue: 0.25 * log2(e)
#define QSCALE 0.36067376022224085f

__device__ inline unsigned short f2bf(float f) {
  union { float f; unsigned u; } v;
  v.f = f;
  unsigned u = v.u;
  u += 0x7fffu + ((u >> 16) & 1u);
  return (unsigned short)(u >> 16);
}

__device__ inline unsigned short f2bf_trunc(float f) {  // RTZ: 1 VALU inst
  union { float f; unsigned u; } v;
  v.f = f;
  return (unsigned short)(v.u >> 16);
}

// ---------------------------------------------------------------------------
// Dtype detector: flag=1 if inputs are fp32, 0 if bf16 (see R2 notes).
// ---------------------------------------------------------------------------
__global__ void detect_kernel(const unsigned short* __restrict__ xr,
                              int* __restrict__ flag) {
  __shared__ int cnt;
  if (threadIdx.x == 0) cnt = 0;
  __syncthreads();
  int local = 0;
  for (int i = threadIdx.x; i < 8192; i += 256) {
    unsigned short u = xr[i];
    if ((u & 0x7F80u) == 0x7F80u) local++;
  }
  if (local) atomicAdd(&cnt, local);
  __syncthreads();
  if (threadIdx.x == 0) *flag = (cnt > 0) ? 1 : 0;
}

__device__ inline float ldin(const void* p, long i, int isf32) {
  if (isf32) return ((const float*)p)[i];
  union { unsigned u; float f; } v;
  v.u = ((unsigned)((const unsigned short*)p)[i]) << 16;
  return v.f;
}

// ---------------------------------------------------------------------------
// R17 prep (verbatim): xconv (zero-LDS streaming) + wrepack (coalesced
// two-stage, 51 KB LDS confined here) + bias block.
// wF layout: [tap][c8(8)][co16(16)][lane(64)][j(8)],
//   co = co16*16 + (lane&15), ci = c8*32 + (lane>>4)*8 + j.
// ---------------------------------------------------------------------------
__global__ __launch_bounds__(256) void xconv_kernel(
    const void* __restrict__ x, unsigned short* __restrict__ xbf,
    const int* __restrict__ flag) {
  const int isf32 = *flag;
  const int i = (blockIdx.x * 256 + threadIdx.x) * 4;
  if (isf32) {
    const float4 v = *(const float4*)((const float*)x + i);
    ushort4 o;
    o.x = f2bf(v.x); o.y = f2bf(v.y); o.z = f2bf(v.z); o.w = f2bf(v.w);
    *(ushort4*)(xbf + i) = o;
  } else {
    *(ushort4*)(xbf + i) = *(const ushort4*)((const unsigned short*)x + i);
  }
}

__device__ inline void frag_repack2(const void* __restrict__ w,
                                    unsigned short* __restrict__ wF, int KK,
                                    int slice, float* __restrict__ Wl,
                                    int isf32) {
  const int t = threadIdx.x;
  const int co16 = slice & 15;
  const int c8   = slice >> 4;
  const int RE = 32 * KK;
  for (int r = 0; r < 16; ++r) {
    const long base = ((long)((co16 * 16 + r) * 256 + c8 * 32)) * KK;
    for (int i = t; i < RE; i += 256) Wl[r * RE + i] = ldin(w, base + i, isf32);
  }
  __syncthreads();
  for (int tap = 0; tap < KK; ++tap) {
    unsigned short* dst = wF + ((((tap << 3) + c8) << 4) + co16) * 512;
    for (int i = t; i < 512; i += 256) {
      const int lane = i >> 3, j = i & 7;
      const int col = lane & 15;
      const int cis = ((lane >> 4) << 3) + j;
      dst[i] = f2bf(Wl[(col * 32 + cis) * KK + tap]);
    }
  }
}

__global__ __launch_bounds__(256) void wrepack_kernel(
    const void* __restrict__ w3, const void* __restrict__ b3,
    const void* __restrict__ w5, const void* __restrict__ b5,
    const void* __restrict__ w7, const void* __restrict__ b7,
    const void* __restrict__ wp,
    unsigned short* __restrict__ wF3, unsigned short* __restrict__ wF5,
    unsigned short* __restrict__ wF7, unsigned short* __restrict__ wpF,
    float* __restrict__ bc, const int* __restrict__ flag) {
  __shared__ float Wl[12800];
  const int isf32 = *flag;
  const int bid = blockIdx.x;
  const int t = threadIdx.x;
  if (bid < 128) {
    frag_repack2(w7, wF7, 25, bid, Wl, isf32);
  } else if (bid < 256) {
    frag_repack2(w5, wF5, 9, bid - 128, Wl, isf32);
  } else if (bid < 384) {
    frag_repack2(w3, wF3, 1, bid - 256, Wl, isf32);
  } else if (bid < 512) {
    frag_repack2(wp, wpF, 1, bid - 384, Wl, isf32);
  } else {
#pragma unroll
    for (int r = 0; r < 3; ++r) {
      const int i = r * 256 + t;
      const void* src = (i < 256) ? b3 : (i < 512) ? b5 : b7;
      bc[i] = ldin(src, i & 255, isf32);
    }
  }
}

// ---------------------------------------------------------------------------
// R18 FUSED q/v/k conv: Tm=256 x Tco=32 (2 co16 tiles), 1 block/CU.
// LDS-read accounting (model validated vs R13 69.7us and R17 49.5us):
// per tap per wave 4 A + 2 B = 6 b128 feeding 8 k-MFMAs -> per-CU reads
// 8640 -> 4800 b128 (-37%). Grid 256 = exactly 1 block/CU, single round.
// B via glds, slot = tap*2+ni (70 slots, wave-uniform base = R13 contract).
// Epilogue = R9/R10-verified 2-co16 algebra. q pre-scaled by QSCALE.
// LDS 106.2 KB. Attention coords (R2/R11-verified): slab=(b<<4)+(co>>4),
//   m=(co&15)*64+(n>>4), d=n&15;  q/k rows: (slab<<14)+((co&15)<<10)+n ;
//   v (V^T): (slab<<14)+((n&15)<<10)+((co&15)<<6)+(n>>4)
// ---------------------------------------------------------------------------
__global__ __launch_bounds__(256, 1) void convqkv_kernel(
    const unsigned short* __restrict__ xbf,
    const unsigned short* __restrict__ wFq,  // 1 tap
    const unsigned short* __restrict__ wFv,  // 9 taps
    const unsigned short* __restrict__ wFk,  // 25 taps
    const float* __restrict__ bc,            // [3][256] q,v,k
    unsigned short* __restrict__ qOut,
    unsigned short* __restrict__ vOut,
    unsigned short* __restrict__ kOut) {
  constexpr int WC = 36;            // halo cols (32 + 2*2)
  constexpr int CELLS = 12 * WC;    // 12 halo rows = 432 cells
  constexpr int LOADS = CELLS * 4;  // 1728 halo dwordx4 loads
  __shared__ unsigned short Xs[CELLS * 40];  // halo [cell][32ci pad40] 34.6KB
  __shared__ unsigned short Bs[70 * 512];    // B [slot70][lane64][8]   71.7KB
  const int t    = threadIdx.x;
  const int bid  = blockIdx.x;
  const int cog0 = (bid & 7) << 1;     // first of 2 co16 tiles
  const int co0  = cog0 << 4;          // 32 co
  const int m0   = (bid >> 3) << 8;    // 256 positions (8 image rows)
  const int b    = m0 >> 10;
  const int n0   = m0 & 1023;
  const int r0   = n0 >> 5;
  const int wv   = t >> 6;             // wave owns rows r0+2wv, r0+2wv+1
  const int lane = t & 63;
  const int l15  = lane & 15;
  const int quad = lane >> 4;

  floatx4 aq[4][2] = {}, av[4][2] = {}, ak[4][2] = {};  // [frag][ni]

  for (int c8 = 0; c8 < 8; ++c8) {
    // ---- halo loads into registers (7 x uint4; R15-proven) ----
    uint4 xreg[7];
#pragma unroll
    for (int rr = 0; rr < 7; ++rr) {
      const int id = rr * 256 + t;
      const int cell = id >> 2, part = id & 3;
      const int hr = cell / WC, wc = cell - hr * WC;
      const int xr = r0 + hr - 2, xc = wc - 2;
      const bool ok = (id < LOADS) && ((unsigned)xr < 32u) &&
                      ((unsigned)xc < 32u);
      const int cr = xr < 0 ? 0 : (xr > 31 ? 31 : xr);
      const int cc = xc < 0 ? 0 : (xc > 31 ? 31 : xc);
      uint4 v = *(const uint4*)&xbf[(((b * 32 + cr) * 32 + cc) << 8) +
                                    (c8 << 5) + (part << 3)];
      if (!ok) v = make_uint4(0, 0, 0, 0);
      xreg[rr] = v;
    }
    __syncthreads();  // all waves done reading previous chunk's Xs/Bs
    // ---- B: 70 slots (tap,ni) via global_load_lds ----
#pragma unroll
    for (int rr = 0; rr < 18; ++rr) {
      const int slot = (rr << 2) + wv;   // wave-uniform
      if (slot < 70) {
        const int tap = slot >> 1, ni = slot & 1;
        const unsigned short* src;
        if (tap < 25) {
          src = &wFk[((((tap << 3) + c8) << 4) + cog0 + ni) * 512];
        } else if (tap < 34) {
          src = &wFv[(((((tap - 25) << 3) + c8) << 4) + cog0 + ni) * 512];
        } else {
          src = &wFq[((c8 << 4) + cog0 + ni) * 512];
        }
        __builtin_amdgcn_global_load_lds((g_u32*)(src + (lane << 3)),
                                         (l_u32*)&Bs[slot << 9], 16, 0, 0);
      }
    }
    // ---- halo regs -> LDS ----
#pragma unroll
    for (int rr = 0; rr < 7; ++rr) {
      const int id = rr * 256 + t;
      if (id < LOADS)
        *(uint4*)&Xs[(id >> 2) * 40 + ((id & 3) << 3)] = xreg[rr];
    }
    __syncthreads();  // drains vmcnt (glds) + lgkm: all ready

    // ---- tap loop: pure LDS + MFMA, no global, no barriers ----
#pragma unroll
    for (int tap = 0; tap < 25; ++tap) {
      const int kh = tap / 5, kw = tap % 5;
      const bool vv = (kh >= 1 && kh <= 3 && kw >= 1 && kw <= 3);
      short8 a[4];
#pragma unroll
      for (int rr2 = 0; rr2 < 2; ++rr2) {
#pragma unroll
        for (int ch = 0; ch < 2; ++ch) {
          const unsigned short* xs =
              &Xs[(((wv << 1) + rr2 + kh) * WC + (ch << 4) + l15 + kw) * 40 +
                  (quad << 3)];
          a[(rr2 << 1) + ch] = *(const short8*)xs;
        }
      }
      const short8 kb0 = *(const short8*)&Bs[((tap << 1) << 9) + (lane << 3)];
      const short8 kb1 =
          *(const short8*)&Bs[(((tap << 1) + 1) << 9) + (lane << 3)];
#pragma unroll
      for (int f = 0; f < 4; ++f) {
        ak[f][0] = __builtin_amdgcn_mfma_f32_16x16x32_bf16(a[f], kb0,
                                                           ak[f][0], 0, 0, 0);
        ak[f][1] = __builtin_amdgcn_mfma_f32_16x16x32_bf16(a[f], kb1,
                                                           ak[f][1], 0, 0, 0);
      }
      if (vv) {
        const int vt = (kh - 1) * 3 + (kw - 1);
        const int vs = 50 + (vt << 1);
        const short8 vb0 = *(const short8*)&Bs[(vs << 9) + (lane << 3)];
        const short8 vb1 = *(const short8*)&Bs[((vs + 1) << 9) + (lane << 3)];
#pragma unroll
        for (int f = 0; f < 4; ++f) {
          av[f][0] = __builtin_amdgcn_mfma_f32_16x16x32_bf16(a[f], vb0,
                                                             av[f][0], 0, 0, 0);
          av[f][1] = __builtin_amdgcn_mfma_f32_16x16x32_bf16(a[f], vb1,
                                                             av[f][1], 0, 0, 0);
        }
      }
      if (tap == 12) {
        const short8 qb0 = *(const short8*)&Bs[(68 << 9) + (lane << 3)];
        const short8 qb1 = *(const short8*)&Bs[(69 << 9) + (lane << 3)];
#pragma unroll
        for (int f = 0; f < 4; ++f) {
          aq[f][0] = __builtin_amdgcn_mfma_f32_16x16x32_bf16(a[f], qb0,
                                                             aq[f][0], 0, 0, 0);
          aq[f][1] = __builtin_amdgcn_mfma_f32_16x16x32_bf16(a[f], qb1,
                                                             aq[f][1], 0, 0, 0);
        }
      }
    }
  }
  // ---- epilogues (R9/R10-verified 2-co16 algebra; R15 nb extension) ----
#pragma unroll
  for (int rr2 = 0; rr2 < 2; ++rr2) {
#pragma unroll
    for (int ch = 0; ch < 2; ++ch) {
      const int f = (rr2 << 1) + ch;
      const int nb = n0 + (wv << 6) + (rr2 << 5) + (ch << 4) + (quad << 2);
#pragma unroll
      for (int ni = 0; ni < 2; ++ni) {
        const int co = co0 + (ni << 4) + l15;
        const int slab = (b << 4) + (co >> 4);
        const int clo = co & 15;
        {
          const float bj = bc[co];
          floatx4 a = aq[f][ni];
          ushort4 pk4;
          pk4.x = f2bf((a[0] + bj) * QSCALE);
          pk4.y = f2bf((a[1] + bj) * QSCALE);
          pk4.z = f2bf((a[2] + bj) * QSCALE);
          pk4.w = f2bf((a[3] + bj) * QSCALE);
          *(ushort4*)&qOut[(slab << 14) + (clo << 10) + nb] = pk4;
        }
        {
          const float bj = bc[512 + co];
          floatx4 a = ak[f][ni];
          ushort4 pk4;
          pk4.x = f2bf(a[0] + bj); pk4.y = f2bf(a[1] + bj);
          pk4.z = f2bf(a[2] + bj); pk4.w = f2bf(a[3] + bj);
          *(ushort4*)&kOut[(slab << 14) + (clo << 10) + nb] = pk4;
        }
        {
          const float bj = bc[256 + co];
          floatx4 a = av[f][ni];
          const int base = (slab << 14) + (clo << 6);
#pragma unroll
          for (int i = 0; i < 4; ++i) {
            const int n = nb + i;
            vOut[base + ((n & 15) << 10) + (n >> 4)] = f2bf(a[i] + bj);
          }
        }
      }
    }
  }
}

// ---------------------------------------------------------------------------
// R17-verified MFMA attention (byte-identical): single-inst exp2, truncating
// bf16 P-store, ones-MFMA row sums, K/V from global, barrier-free, 10.2 KB.
// ---------------------------------------------------------------------------
__global__ __launch_bounds__(256, 4) void attn_mfma_kernel(
    const unsigned short* __restrict__ qg,
    const unsigned short* __restrict__ kg,
    const unsigned short* __restrict__ vg,
    unsigned short* __restrict__ out2) {
  __shared__ __align__(16) unsigned short Pb[4][32][40];  // per-wave P
  const int t    = threadIdx.x;
  const int w    = t >> 6;
  const int lane = t & 63;
  const int slab = blockIdx.x >> 3;
  const int rb   = blockIdx.x & 7;
  const int b = slab >> 4;
  const int h = slab & 15;
  const int l31  = lane & 31;
  const int hl   = lane >> 5;
  const int l15  = lane & 15;
  const int quad = lane >> 4;

  const unsigned short* Kb = kg + (slab << 14);
  const unsigned short* Vb = vg + (slab << 14);

  const int row0 = (rb << 7) + (w << 5);
  const short8 qa =
      *(const short8*)&qg[(slab << 14) + ((row0 + l31) << 4) + (hl << 3)];

  const short onebf = (short)0x3F80;  // bf16 1.0
  const short8 ones = {onebf, onebf, onebf, onebf, onebf, onebf, onebf, onebf};

  floatx4 acco[2] = {}, asum[2] = {};

  for (int kc = 0; kc < 1024; kc += 32) {
    const short8 kb = *(const short8*)&Kb[((kc + l31) << 4) + (hl << 3)];
    floatx16 s = {};
    s = __builtin_amdgcn_mfma_f32_32x32x16_bf16(qa, kb, s, 0, 0, 0);
#pragma unroll
    for (int r = 0; r < 16; ++r) {
      const float e = __builtin_amdgcn_exp2f(s[r]);  // scale pre-folded in Q
      const int row = (r & 3) + ((r >> 2) << 3) + (hl << 2);
      Pb[w][row][l31] = f2bf_trunc(e);
    }
    const short8 vb = *(const short8*)&Vb[(l15 << 10) + kc + (quad << 3)];
#pragma unroll
    for (int tt = 0; tt < 2; ++tt) {
      const short8 pa = *(const short8*)&Pb[w][(tt << 4) + l15][quad << 3];
      acco[tt] =
          __builtin_amdgcn_mfma_f32_16x16x32_bf16(pa, vb, acco[tt], 0, 0, 0);
      asum[tt] =
          __builtin_amdgcn_mfma_f32_16x16x32_bf16(pa, ones, asum[tt], 0, 0, 0);
    }
  }
#pragma unroll
  for (int tt = 0; tt < 2; ++tt) {
#pragma unroll
    for (int r = 0; r < 4; ++r) {
      const int nloc = (tt << 4) + (quad << 2) + r;
      const float val = acco[tt][r] / asum[tt][r];
      const int n = row0 + nloc;
      out2[(((b << 10) + n) << 8) + (h << 4) + l15] = f2bf(val);
    }
  }
}

// ---------------------------------------------------------------------------
// Final linear, MFMA bf16, with one-chunk-ahead B register prefetch.
// ---------------------------------------------------------------------------
__global__ __launch_bounds__(256) void linear_mfma_kernel(
    const unsigned short* __restrict__ inp,  // bf16 [8192][256]
    const unsigned short* __restrict__ wpF,  // fragment order
    void* __restrict__ out, const int* __restrict__ flag) {
  __shared__ unsigned short As[64 * 40];
  const int isf32 = *flag;
  const int t   = threadIdx.x;
  const int m0  = blockIdx.x << 6;
  const int co0 = blockIdx.y << 6;
  const int wv   = t >> 6;
  const int lane = t & 63;
  const int wm = (wv & 1) << 5;
  const int wn = (wv >> 1) << 5;
  const int l15  = lane & 15;
  const int quad = lane >> 4;
  const int cogb = (co0 >> 4) + (wn >> 4);
  const int rowS = t >> 2;
  const int partS = t & 3;

  floatx4 acc[2][2] = {};

  short8 cb0, cb1;
  {
    const unsigned short* wptr = &wpF[(cogb << 9) + (lane << 3)];
    cb0 = *(const short8*)wptr;
    cb1 = *(const short8*)(wptr + 512);
  }
  for (int c8 = 0; c8 < 8; ++c8) {
    const uint4 v = *(const uint4*)&inp[((m0 + rowS) << 8) + (c8 << 5) +
                                        (partS << 3)];
    short8 nb0 = {}, nb1 = {};
    if (c8 + 1 < 8) {
      const unsigned short* wptr =
          &wpF[((((c8 + 1) << 4) + cogb) << 9) + (lane << 3)];
      nb0 = *(const short8*)wptr;
      nb1 = *(const short8*)(wptr + 512);
    }
    __syncthreads();
    *(uint4*)&As[rowS * 40 + (partS << 3)] = v;
    __syncthreads();
    const unsigned short* xs = &As[(wm + l15) * 40 + (quad << 3)];
    const short8 afr0 = *(const short8*)xs;
    const short8 afr1 = *(const short8*)(xs + 16 * 40);
    acc[0][0] = __builtin_amdgcn_mfma_f32_16x16x32_bf16(afr0, cb0,
                                                        acc[0][0], 0, 0, 0);
    acc[0][1] = __builtin_amdgcn_mfma_f32_16x16x32_bf16(afr0, cb1,
                                                        acc[0][1], 0, 0, 0);
    acc[1][0] = __builtin_amdgcn_mfma_f32_16x16x32_bf16(afr1, cb0,
                                                        acc[1][0], 0, 0, 0);
    acc[1][1] = __builtin_amdgcn_mfma_f32_16x16x32_bf16(afr1, cb1,
                                                        acc[1][1], 0, 0, 0);
    cb0 = nb0; cb1 = nb1;
  }
#pragma unroll
  for (int mi = 0; mi < 2; ++mi) {
#pragma unroll
    for (int ni = 0; ni < 2; ++ni) {
      const int co = co0 + wn + (ni << 4) + l15;
      const int mb = m0 + wm + (mi << 4) + (quad << 2);
      floatx4 a = acc[mi][ni];
      if (!isf32) {
        unsigned short* o16 = (unsigned short*)out;
#pragma unroll
        for (int r = 0; r < 4; ++r) o16[(mb + r) * 256 + co] = f2bf(a[r]);
      } else {
        float* o32 = (float*)out;
#pragma unroll
        for (int r = 0; r < 4; ++r) o32[(mb + r) * 256 + co] = a[r];
      }
    }
  }
}

// ---------------------------------------------------------------------------
extern "C" void kernel_launch(void* const* d_in, const int* in_sizes, int n_in,
                              void* d_out, int out_size, void* d_ws,
                              size_t ws_size, hipStream_t stream) {
  const void* x  = d_in[0];
  const void* w3 = d_in[1];
  const void* b3 = d_in[2];
  const void* w5 = d_in[3];
  const void* b5 = d_in[4];
  const void* w7 = d_in[5];
  const void* b7 = d_in[6];
  const void* wp = d_in[7];

  char* p = (char*)d_ws;
  int* flag = (int*)p;                       p += 256;
  unsigned short* xbf = (unsigned short*)p;  p += 4u * 1024 * 1024;
  unsigned short* wF3 = (unsigned short*)p;  p += 131072;
  unsigned short* wF5 = (unsigned short*)p;  p += 1179648;
  unsigned short* wF7 = (unsigned short*)p;  p += 3276800;
  unsigned short* wpF = (unsigned short*)p;  p += 131072;
  float* bc = (float*)p;                     p += 4096;     // [3][256]
  unsigned short* qc  = (unsigned short*)p;  p += 4194304;  // bf16 QK rows
  unsigned short* kT  = (unsigned short*)p;  p += 4194304;  // bf16 QK rows
  unsigned short* vT  = (unsigned short*)p;  p += 4194304;  // bf16 V^T
  unsigned short* o2b = (unsigned short*)p;  p += 4194304;  // bf16 [8192][256]

  detect_kernel<<<1, 256, 0, stream>>>((const unsigned short*)x, flag);

  xconv_kernel<<<2048, 256, 0, stream>>>(x, xbf, flag);
  wrepack_kernel<<<513, 256, 0, stream>>>(w3, b3, w5, b5, w7, b7, wp, wF3,
                                          wF5, wF7, wpF, bc, flag);

  convqkv_kernel<<<256, 256, 0, stream>>>(xbf, wF3, wF5, wF7, bc, qc, vT, kT);

  attn_mfma_kernel<<<1024, 256, 0, stream>>>(qc, kT, vT, o2b);

  dim3 lg(128, 4);
  linear_mfma_kernel<<<lg, 256, 0, stream>>>(o2b, wpF, d_out, flag);
}

// Round 19
// 179.135 us; speedup vs baseline: 1.0559x; 1.0559x over previous
//
#include <hip/hip_runtime.h>
#include <hip/hip_bf16.h>

#define DIM 256
#define HW  1024  // 32*32

typedef __attribute__((ext_vector_type(8))) short short8;
typedef __attribute__((ext_vector_type(4))) float floatx4;
typedef __attribute__((ext_vector_type(16))) float floatx16;
typedef __attribute__((address_space(1))) const unsigned int g_u32;
typedef __attribute__((address_space(3))) unsigned int l_u32;

// softmax scale folded into Q at conv epilogue: 0.25 * log2(e)
#define QSCALE 0.36067376022224085f

__device__ inline unsigned short f2bf(float f) {
  union { float f; unsigned u; } v;
  v.f = f;
  unsigned u = v.u;
  u += 0x7fffu + ((u >> 16) & 1u);
  return (unsigned short)(u >> 16);
}

__device__ inline unsigned short f2bf_trunc(float f) {  // RTZ: 1 VALU inst
  union { float f; unsigned u; } v;
  v.f = f;
  return (unsigned short)(v.u >> 16);
}

// ---------------------------------------------------------------------------
// Dtype detector: flag=1 if inputs are fp32, 0 if bf16 (see R2 notes).
// ---------------------------------------------------------------------------
__global__ void detect_kernel(const unsigned short* __restrict__ xr,
                              int* __restrict__ flag) {
  __shared__ int cnt;
  if (threadIdx.x == 0) cnt = 0;
  __syncthreads();
  int local = 0;
  for (int i = threadIdx.x; i < 8192; i += 256) {
    unsigned short u = xr[i];
    if ((u & 0x7F80u) == 0x7F80u) local++;
  }
  if (local) atomicAdd(&cnt, local);
  __syncthreads();
  if (threadIdx.x == 0) *flag = (cnt > 0) ? 1 : 0;
}

__device__ inline float ldin(const void* p, long i, int isf32) {
  if (isf32) return ((const float*)p)[i];
  union { unsigned u; float f; } v;
  v.u = ((unsigned)((const unsigned short*)p)[i]) << 16;
  return v.f;
}

// ---------------------------------------------------------------------------
// Prep: xconv (zero-LDS streaming) + wrepack (coalesced two-stage).
// R19 fix: Wl row stride RE -> RE+1. With RE=800 (== 0 mod 32) the stage-2
// gather addr (col*32+cis)*KK+tap had ZERO bank spread from col -> 8-way
// conflicts on every read; stride 801 (== 1 mod 32) spreads col across all
// banks. Pure layout change; output algebra identical (re-verified by
// substitution).
// wF layout: [tap][c8(8)][co16(16)][lane(64)][j(8)],
//   co = co16*16 + (lane&15), ci = c8*32 + (lane>>4)*8 + j.
// ---------------------------------------------------------------------------
__global__ __launch_bounds__(256) void xconv_kernel(
    const void* __restrict__ x, unsigned short* __restrict__ xbf,
    const int* __restrict__ flag) {
  const int isf32 = *flag;
  const int i = (blockIdx.x * 256 + threadIdx.x) * 4;
  if (isf32) {
    const float4 v = *(const float4*)((const float*)x + i);
    ushort4 o;
    o.x = f2bf(v.x); o.y = f2bf(v.y); o.z = f2bf(v.z); o.w = f2bf(v.w);
    *(ushort4*)(xbf + i) = o;
  } else {
    *(ushort4*)(xbf + i) = *(const ushort4*)((const unsigned short*)x + i);
  }
}

__device__ inline void frag_repack2(const void* __restrict__ w,
                                    unsigned short* __restrict__ wF, int KK,
                                    int slice, float* __restrict__ Wl,
                                    int isf32) {
  const int t = threadIdx.x;
  const int co16 = slice & 15;
  const int c8   = slice >> 4;
  const int RE = 32 * KK;           // elems per co row (contiguous in source)
  const int RS = RE + 1;            // padded LDS row stride (bank spread)
  for (int r = 0; r < 16; ++r) {
    const long base = ((long)((co16 * 16 + r) * 256 + c8 * 32)) * KK;
    for (int i = t; i < RE; i += 256) Wl[r * RS + i] = ldin(w, base + i, isf32);
  }
  __syncthreads();
  for (int tap = 0; tap < KK; ++tap) {
    unsigned short* dst = wF + ((((tap << 3) + c8) << 4) + co16) * 512;
    for (int i = t; i < 512; i += 256) {
      const int lane = i >> 3, j = i & 7;
      const int col = lane & 15;
      const int cis = ((lane >> 4) << 3) + j;
      dst[i] = f2bf(Wl[col * RS + cis * KK + tap]);
    }
  }
}

__global__ __launch_bounds__(256) void wrepack_kernel(
    const void* __restrict__ w3, const void* __restrict__ b3,
    const void* __restrict__ w5, const void* __restrict__ b5,
    const void* __restrict__ w7, const void* __restrict__ b7,
    const void* __restrict__ wp,
    unsigned short* __restrict__ wF3, unsigned short* __restrict__ wF5,
    unsigned short* __restrict__ wF7, unsigned short* __restrict__ wpF,
    float* __restrict__ bc, const int* __restrict__ flag) {
  __shared__ float Wl[12816];  // 16 x (800+1) max
  const int isf32 = *flag;
  const int bid = blockIdx.x;
  const int t = threadIdx.x;
  if (bid < 128) {
    frag_repack2(w7, wF7, 25, bid, Wl, isf32);
  } else if (bid < 256) {
    frag_repack2(w5, wF5, 9, bid - 128, Wl, isf32);
  } else if (bid < 384) {
    frag_repack2(w3, wF3, 1, bid - 256, Wl, isf32);
  } else if (bid < 512) {
    frag_repack2(wp, wpF, 1, bid - 384, Wl, isf32);
  } else {
#pragma unroll
    for (int r = 0; r < 3; ++r) {
      const int i = r * 256 + t;
      const void* src = (i < 256) ? b3 : (i < 512) ? b5 : b7;
      bc[i] = ldin(src, i & 255, isf32);
    }
  }
}

// ---------------------------------------------------------------------------
// R17-verified FUSED q/v/k conv (reverted verbatim from R18's Tco=32
// regression — 1 block/CU exposed staging latency; Tco=16 @ 2 blocks/CU is
// the validated optimum ~49.5us). Tm=256, wave owns 2 image rows.
// q epilogue pre-scales by QSCALE. B via global_load_lds(16B).
// LDS 71.4 KB -> 2 blocks/CU; grid 512.
// Attention coords (R2/R11-verified): slab=(b<<4)+(co>>4), m=(co&15)*64+(n>>4),
//   d=n&15;  q/k rows: (slab<<14)+((co&15)<<10)+n ;  v (V^T):
//   (slab<<14)+((n&15)<<10)+((co&15)<<6)+(n>>4)
// ---------------------------------------------------------------------------
__global__ __launch_bounds__(256, 2) void convqkv_kernel(
    const unsigned short* __restrict__ xbf,
    const unsigned short* __restrict__ wFq,  // 1 tap
    const unsigned short* __restrict__ wFv,  // 9 taps
    const unsigned short* __restrict__ wFk,  // 25 taps
    const float* __restrict__ bc,            // [3][256] q,v,k
    unsigned short* __restrict__ qOut,
    unsigned short* __restrict__ vOut,
    unsigned short* __restrict__ kOut) {
  constexpr int WC = 36;            // halo cols (32 + 2*2)
  constexpr int CELLS = 12 * WC;    // 12 halo rows = 432 cells
  constexpr int LOADS = CELLS * 4;  // 1728 halo dwordx4 loads
  __shared__ unsigned short Xs[CELLS * 40];  // halo [cell][32ci pad40] 34.6KB
  __shared__ unsigned short Bs[36 * 512];    // B [tap35+1][lane64][8]  36.9KB
  const int t    = threadIdx.x;
  const int bid  = blockIdx.x;
  const int cog0 = bid & 15;
  const int co0  = cog0 << 4;
  const int m0   = (bid >> 4) << 8;    // 256 positions (8 image rows)
  const int b    = m0 >> 10;
  const int n0   = m0 & 1023;
  const int r0   = n0 >> 5;
  const int wv   = t >> 6;
  const int lane = t & 63;
  const int l15  = lane & 15;
  const int quad = lane >> 4;

  floatx4 aq[4] = {}, av[4] = {}, ak[4] = {};

  for (int c8 = 0; c8 < 8; ++c8) {
    uint4 xreg[7];
#pragma unroll
    for (int rr = 0; rr < 7; ++rr) {
      const int id = rr * 256 + t;
      const int cell = id >> 2, part = id & 3;
      const int hr = cell / WC, wc = cell - hr * WC;
      const int xr = r0 + hr - 2, xc = wc - 2;
      const bool ok = (id < LOADS) && ((unsigned)xr < 32u) &&
                      ((unsigned)xc < 32u);
      const int cr = xr < 0 ? 0 : (xr > 31 ? 31 : xr);
      const int cc = xc < 0 ? 0 : (xc > 31 ? 31 : xc);
      uint4 v = *(const uint4*)&xbf[(((b * 32 + cr) * 32 + cc) << 8) +
                                    (c8 << 5) + (part << 3)];
      if (!ok) v = make_uint4(0, 0, 0, 0);
      xreg[rr] = v;
    }
    __syncthreads();
#pragma unroll
    for (int rr = 0; rr < 9; ++rr) {
      const int tap = (rr << 2) + wv;
      if (tap < 35) {
        const unsigned short* src;
        if (tap < 25) {
          src = &wFk[((((tap << 3) + c8) << 4) + cog0) * 512];
        } else if (tap < 34) {
          src = &wFv[(((((tap - 25) << 3) + c8) << 4) + cog0) * 512];
        } else {
          src = &wFq[((c8 << 4) + cog0) * 512];
        }
        __builtin_amdgcn_global_load_lds((g_u32*)(src + (lane << 3)),
                                         (l_u32*)&Bs[tap << 9], 16, 0, 0);
      }
    }
#pragma unroll
    for (int rr = 0; rr < 7; ++rr) {
      const int id = rr * 256 + t;
      if (id < LOADS)
        *(uint4*)&Xs[(id >> 2) * 40 + ((id & 3) << 3)] = xreg[rr];
    }
    __syncthreads();

#pragma unroll
    for (int tap = 0; tap < 25; ++tap) {
      const int kh = tap / 5, kw = tap % 5;
      const bool vv = (kh >= 1 && kh <= 3 && kw >= 1 && kw <= 3);
      short8 a[4];
#pragma unroll
      for (int rr2 = 0; rr2 < 2; ++rr2) {
#pragma unroll
        for (int ch = 0; ch < 2; ++ch) {
          const unsigned short* xs =
              &Xs[(((wv << 1) + rr2 + kh) * WC + (ch << 4) + l15 + kw) * 40 +
                  (quad << 3)];
          a[(rr2 << 1) + ch] = *(const short8*)xs;
        }
      }
      const short8 kb = *(const short8*)&Bs[(tap << 9) + (lane << 3)];
#pragma unroll
      for (int f = 0; f < 4; ++f)
        ak[f] = __builtin_amdgcn_mfma_f32_16x16x32_bf16(a[f], kb, ak[f],
                                                        0, 0, 0);
      if (vv) {
        const int vt = (kh - 1) * 3 + (kw - 1);
        const short8 vb = *(const short8*)&Bs[((25 + vt) << 9) + (lane << 3)];
#pragma unroll
        for (int f = 0; f < 4; ++f)
          av[f] = __builtin_amdgcn_mfma_f32_16x16x32_bf16(a[f], vb, av[f],
                                                          0, 0, 0);
      }
      if (tap == 12) {
        const short8 qb = *(const short8*)&Bs[(34 << 9) + (lane << 3)];
#pragma unroll
        for (int f = 0; f < 4; ++f)
          aq[f] = __builtin_amdgcn_mfma_f32_16x16x32_bf16(a[f], qb, aq[f],
                                                          0, 0, 0);
      }
    }
  }
#pragma unroll
  for (int rr2 = 0; rr2 < 2; ++rr2) {
#pragma unroll
    for (int ch = 0; ch < 2; ++ch) {
      const int f = (rr2 << 1) + ch;
      const int co = co0 + l15;
      const int slab = (b << 4) + (co >> 4);
      const int clo = co & 15;
      const int nb = n0 + (wv << 6) + (rr2 << 5) + (ch << 4) + (quad << 2);
      {
        const float bj = bc[co];
        floatx4 a = aq[f];
        ushort4 pk4;
        pk4.x = f2bf((a[0] + bj) * QSCALE);
        pk4.y = f2bf((a[1] + bj) * QSCALE);
        pk4.z = f2bf((a[2] + bj) * QSCALE);
        pk4.w = f2bf((a[3] + bj) * QSCALE);
        *(ushort4*)&qOut[(slab << 14) + (clo << 10) + nb] = pk4;
      }
      {
        const float bj = bc[512 + co];
        floatx4 a = ak[f];
        ushort4 pk4;
        pk4.x = f2bf(a[0] + bj); pk4.y = f2bf(a[1] + bj);
        pk4.z = f2bf(a[2] + bj); pk4.w = f2bf(a[3] + bj);
        *(ushort4*)&kOut[(slab << 14) + (clo << 10) + nb] = pk4;
      }
      {
        const float bj = bc[256 + co];
        floatx4 a = av[f];
        const int base = (slab << 14) + (clo << 6);
#pragma unroll
        for (int i = 0; i < 4; ++i) {
          const int n = nb + i;
          vOut[base + ((n & 15) << 10) + (n >> 4)] = f2bf(a[i] + bj);
        }
      }
    }
  }
}

// ---------------------------------------------------------------------------
// R17-verified MFMA attention (byte-identical): single-inst exp2, truncating
// bf16 P-store, ones-MFMA row sums, K/V from global, barrier-free, 10.2 KB.
// ---------------------------------------------------------------------------
__global__ __launch_bounds__(256, 4) void attn_mfma_kernel(
    const unsigned short* __restrict__ qg,
    const unsigned short* __restrict__ kg,
    const unsigned short* __restrict__ vg,
    unsigned short* __restrict__ out2) {
  __shared__ __align__(16) unsigned short Pb[4][32][40];  // per-wave P
  const int t    = threadIdx.x;
  const int w    = t >> 6;
  const int lane = t & 63;
  const int slab = blockIdx.x >> 3;
  const int rb   = blockIdx.x & 7;
  const int b = slab >> 4;
  const int h = slab & 15;
  const int l31  = lane & 31;
  const int hl   = lane >> 5;
  const int l15  = lane & 15;
  const int quad = lane >> 4;

  const unsigned short* Kb = kg + (slab << 14);
  const unsigned short* Vb = vg + (slab << 14);

  const int row0 = (rb << 7) + (w << 5);
  const short8 qa =
      *(const short8*)&qg[(slab << 14) + ((row0 + l31) << 4) + (hl << 3)];

  const short onebf = (short)0x3F80;  // bf16 1.0
  const short8 ones = {onebf, onebf, onebf, onebf, onebf, onebf, onebf, onebf};

  floatx4 acco[2] = {}, asum[2] = {};

  for (int kc = 0; kc < 1024; kc += 32) {
    const short8 kb = *(const short8*)&Kb[((kc + l31) << 4) + (hl << 3)];
    floatx16 s = {};
    s = __builtin_amdgcn_mfma_f32_32x32x16_bf16(qa, kb, s, 0, 0, 0);
#pragma unroll
    for (int r = 0; r < 16; ++r) {
      const float e = __builtin_amdgcn_exp2f(s[r]);  // scale pre-folded in Q
      const int row = (r & 3) + ((r >> 2) << 3) + (hl << 2);
      Pb[w][row][l31] = f2bf_trunc(e);
    }
    const short8 vb = *(const short8*)&Vb[(l15 << 10) + kc + (quad << 3)];
#pragma unroll
    for (int tt = 0; tt < 2; ++tt) {
      const short8 pa = *(const short8*)&Pb[w][(tt << 4) + l15][quad << 3];
      acco[tt] =
          __builtin_amdgcn_mfma_f32_16x16x32_bf16(pa, vb, acco[tt], 0, 0, 0);
      asum[tt] =
          __builtin_amdgcn_mfma_f32_16x16x32_bf16(pa, ones, asum[tt], 0, 0, 0);
    }
  }
#pragma unroll
  for (int tt = 0; tt < 2; ++tt) {
#pragma unroll
    for (int r = 0; r < 4; ++r) {
      const int nloc = (tt << 4) + (quad << 2) + r;
      const float val = acco[tt][r] / asum[tt][r];
      const int n = row0 + nloc;
      out2[(((b << 10) + n) << 8) + (h << 4) + l15] = f2bf(val);
    }
  }
}

// ---------------------------------------------------------------------------
// Final linear, MFMA bf16, with one-chunk-ahead B register prefetch.
// ---------------------------------------------------------------------------
__global__ __launch_bounds__(256) void linear_mfma_kernel(
    const unsigned short* __restrict__ inp,  // bf16 [8192][256]
    const unsigned short* __restrict__ wpF,  // fragment order
    void* __restrict__ out, const int* __restrict__ flag) {
  __shared__ unsigned short As[64 * 40];
  const int isf32 = *flag;
  const int t   = threadIdx.x;
  const int m0  = blockIdx.x << 6;
  const int co0 = blockIdx.y << 6;
  const int wv   = t >> 6;
  const int lane = t & 63;
  const int wm = (wv & 1) << 5;
  const int wn = (wv >> 1) << 5;
  const int l15  = lane & 15;
  const int quad = lane >> 4;
  const int cogb = (co0 >> 4) + (wn >> 4);
  const int rowS = t >> 2;
  const int partS = t & 3;

  floatx4 acc[2][2] = {};

  short8 cb0, cb1;
  {
    const unsigned short* wptr = &wpF[(cogb << 9) + (lane << 3)];
    cb0 = *(const short8*)wptr;
    cb1 = *(const short8*)(wptr + 512);
  }
  for (int c8 = 0; c8 < 8; ++c8) {
    const uint4 v = *(const uint4*)&inp[((m0 + rowS) << 8) + (c8 << 5) +
                                        (partS << 3)];
    short8 nb0 = {}, nb1 = {};
    if (c8 + 1 < 8) {
      const unsigned short* wptr =
          &wpF[((((c8 + 1) << 4) + cogb) << 9) + (lane << 3)];
      nb0 = *(const short8*)wptr;
      nb1 = *(const short8*)(wptr + 512);
    }
    __syncthreads();
    *(uint4*)&As[rowS * 40 + (partS << 3)] = v;
    __syncthreads();
    const unsigned short* xs = &As[(wm + l15) * 40 + (quad << 3)];
    const short8 afr0 = *(const short8*)xs;
    const short8 afr1 = *(const short8*)(xs + 16 * 40);
    acc[0][0] = __builtin_amdgcn_mfma_f32_16x16x32_bf16(afr0, cb0,
                                                        acc[0][0], 0, 0, 0);
    acc[0][1] = __builtin_amdgcn_mfma_f32_16x16x32_bf16(afr0, cb1,
                                                        acc[0][1], 0, 0, 0);
    acc[1][0] = __builtin_amdgcn_mfma_f32_16x16x32_bf16(afr1, cb0,
                                                        acc[1][0], 0, 0, 0);
    acc[1][1] = __builtin_amdgcn_mfma_f32_16x16x32_bf16(afr1, cb1,
                                                        acc[1][1], 0, 0, 0);
    cb0 = nb0; cb1 = nb1;
  }
#pragma unroll
  for (int mi = 0; mi < 2; ++mi) {
#pragma unroll
    for (int ni = 0; ni < 2; ++ni) {
      const int co = co0 + wn + (ni << 4) + l15;
      const int mb = m0 + wm + (mi << 4) + (quad << 2);
      floatx4 a = acc[mi][ni];
      if (!isf32) {
        unsigned short* o16 = (unsigned short*)out;
#pragma unroll
        for (int r = 0; r < 4; ++r) o16[(mb + r) * 256 + co] = f2bf(a[r]);
      } else {
        float* o32 = (float*)out;
#pragma unroll
        for (int r = 0; r < 4; ++r) o32[(mb + r) * 256 + co] = a[r];
      }
    }
  }
}

// ---------------------------------------------------------------------------
extern "C" void kernel_launch(void* const* d_in, const int* in_sizes, int n_in,
                              void* d_out, int out_size, void* d_ws,
                              size_t ws_size, hipStream_t stream) {
  const void* x  = d_in[0];
  const void* w3 = d_in[1];
  const void* b3 = d_in[2];
  const void* w5 = d_in[3];
  const void* b5 = d_in[4];
  const void* w7 = d_in[5];
  const void* b7 = d_in[6];
  const void* wp = d_in[7];

  char* p = (char*)d_ws;
  int* flag = (int*)p;                       p += 256;
  unsigned short* xbf = (unsigned short*)p;  p += 4u * 1024 * 1024;
  unsigned short* wF3 = (unsigned short*)p;  p += 131072;
  unsigned short* wF5 = (unsigned short*)p;  p += 1179648;
  unsigned short* wF7 = (unsigned short*)p;  p += 3276800;
  unsigned short* wpF = (unsigned short*)p;  p += 131072;
  float* bc = (float*)p;                     p += 4096;     // [3][256]
  unsigned short* qc  = (unsigned short*)p;  p += 4194304;  // bf16 QK rows
  unsigned short* kT  = (unsigned short*)p;  p += 4194304;  // bf16 QK rows
  unsigned short* vT  = (unsigned short*)p;  p += 4194304;  // bf16 V^T
  unsigned short* o2b = (unsigned short*)p;  p += 4194304;  // bf16 [8192][256]

  detect_kernel<<<1, 256, 0, stream>>>((const unsigned short*)x, flag);

  xconv_kernel<<<2048, 256, 0, stream>>>(x, xbf, flag);
  wrepack_kernel<<<513, 256, 0, stream>>>(w3, b3, w5, b5, w7, b7, wp, wF3,
                                          wF5, wF7, wpF, bc, flag);

  convqkv_kernel<<<512, 256, 0, stream>>>(xbf, wF3, wF5, wF7, bc, qc, vT, kT);

  attn_mfma_kernel<<<1024, 256, 0, stream>>>(qc, kT, vT, o2b);

  dim3 lg(128, 4);
  linear_mfma_kernel<<<lg, 256, 0, stream>>>(o2b, wpF, d_out, flag);
}

// Round 21
// 174.291 us; speedup vs baseline: 1.0852x; 1.0278x over previous
//
#include <hip/hip_runtime.h>
#include <hip/hip_bf16.h>

#define DIM 256
#define HW  1024  // 32*32

typedef __attribute__((ext_vector_type(8))) short short8;
typedef __attribute__((ext_vector_type(4))) float floatx4;
typedef __attribute__((ext_vector_type(16))) float floatx16;
typedef __attribute__((address_space(1))) const unsigned int g_u32;
typedef __attribute__((address_space(3))) unsigned int l_u32;

// softmax scale folded into Q at conv epilogue: 0.25 * log2(e)
#define QSCALE 0.36067376022224085f

__device__ inline unsigned short f2bf(float f) {
  union { float f; unsigned u; } v;
  v.f = f;
  unsigned u = v.u;
  u += 0x7fffu + ((u >> 16) & 1u);
  return (unsigned short)(u >> 16);
}

__device__ inline unsigned short f2bf_trunc(float f) {  // RTZ: 1 VALU inst
  union { float f; unsigned u; } v;
  v.f = f;
  return (unsigned short)(v.u >> 16);
}

__device__ inline float ldin(const void* p, long i, int isf32) {
  if (isf32) return ((const float*)p)[i];
  union { unsigned u; float f; } v;
  v.u = ((unsigned)((const unsigned short*)p)[i]) << 16;
  return v.f;
}

// ---------------------------------------------------------------------------
// R21 fused prep (R20 with the xconv OOB index FIXED: was (bid*4096+r*1024+t)
// addressing 4x past x's end -> abort; now (bid*1024+r*256+t), exact cover).
//  - every block runs an inline dtype scan over the SAME first 8192 ushorts
//    of x (L2-hot; identical verdict in all blocks).
//  - bid<512   : xconv, 16 elems/thread.
//  - 512..1023 : wrepack, 4-co-row sliced two-stage (LDS 12.8 KB).
//  - bid 1024  : biases + publishes flag for linear.
// wF layout (unchanged): [tap][c8(8)][co16(16)][lane(64)][j(8)],
//   co = co16*16 + (lane&15), ci = c8*32 + (lane>>4)*8 + j.
// ---------------------------------------------------------------------------
__device__ inline int detect_inline(const unsigned short* __restrict__ xr,
                                    int* cnt) {
  if (threadIdx.x == 0) *cnt = 0;
  __syncthreads();
  int local = 0;
  for (int i = threadIdx.x; i < 8192; i += 256) {
    unsigned short u = xr[i];
    if ((u & 0x7F80u) == 0x7F80u) local++;
  }
  if (local) atomicAdd(cnt, local);
  __syncthreads();
  return (*cnt > 0) ? 1 : 0;
}

__device__ inline void frag_repack4(const void* __restrict__ w,
                                    unsigned short* __restrict__ wF, int KK,
                                    int slice, float* __restrict__ Wl,
                                    int isf32) {
  const int t = threadIdx.x;
  const int co16 = slice & 15;
  const int c8   = slice >> 4;
  const int RE = 32 * KK;   // elems per co row (contiguous in source)
  const int RS = RE + 1;    // padded LDS row stride (801 max == 1 mod 32)
  for (int g = 0; g < 4; ++g) {       // 4 co rows per pass
    __syncthreads();                  // previous pass's reads done
    for (int rloc = 0; rloc < 4; ++rloc) {
      const long base =
          ((long)((co16 * 16 + (g << 2) + rloc) * 256 + c8 * 32)) * KK;
      for (int i = t; i < RE; i += 256)
        Wl[rloc * RS + i] = ldin(w, base + i, isf32);
    }
    __syncthreads();
    for (int tap = 0; tap < KK; ++tap) {
      unsigned short* dst = wF + ((((tap << 3) + c8) << 4) + co16) * 512;
      if (t < 128) {
        const int colg = t >> 5;          // local co row 0..3
        const int cis  = t & 31;          // ci-sub 0..31
        const int col  = (g << 2) + colg; // co within co16 tile
        const int lane = ((cis >> 3) << 4) | col;
        const int j    = cis & 7;
        dst[lane * 8 + j] = f2bf(Wl[colg * RS + cis * KK + tap]);
      }
    }
  }
}

__global__ __launch_bounds__(256) void prep_kernel(
    const void* __restrict__ x,  const void* __restrict__ w3,
    const void* __restrict__ b3, const void* __restrict__ w5,
    const void* __restrict__ b5, const void* __restrict__ w7,
    const void* __restrict__ b7, const void* __restrict__ wp,
    unsigned short* __restrict__ xbf,
    unsigned short* __restrict__ wF3, unsigned short* __restrict__ wF5,
    unsigned short* __restrict__ wF7, unsigned short* __restrict__ wpF,
    float* __restrict__ bc, int* __restrict__ flag) {
  __shared__ float Wl[4 * 801];  // 12.8 KB
  __shared__ int cnt;
  const int isf32 = detect_inline((const unsigned short*)x, &cnt);
  const int bid = blockIdx.x;
  const int t = threadIdx.x;
  if (bid < 512) {  // xconv: 16 elems/thread, 4 coalesced rounds
#pragma unroll
    for (int r = 0; r < 4; ++r) {
      const int i = (bid * 1024 + r * 256 + t) * 4;  // FIXED (was 4x OOB)
      if (isf32) {
        const float4 v = *(const float4*)((const float*)x + i);
        ushort4 o;
        o.x = f2bf(v.x); o.y = f2bf(v.y); o.z = f2bf(v.z); o.w = f2bf(v.w);
        *(ushort4*)(xbf + i) = o;
      } else {
        *(ushort4*)(xbf + i) =
            *(const ushort4*)((const unsigned short*)x + i);
      }
    }
  } else if (bid < 640) {
    frag_repack4(w7, wF7, 25, bid - 512, Wl, isf32);
  } else if (bid < 768) {
    frag_repack4(w5, wF5, 9, bid - 640, Wl, isf32);
  } else if (bid < 896) {
    frag_repack4(w3, wF3, 1, bid - 768, Wl, isf32);
  } else if (bid < 1024) {
    frag_repack4(wp, wpF, 1, bid - 896, Wl, isf32);
  } else {  // biases (q=b3, v=b5, k=b7) + publish flag
#pragma unroll
    for (int r = 0; r < 3; ++r) {
      const int i = r * 256 + t;
      const void* src = (i < 256) ? b3 : (i < 512) ? b5 : b7;
      bc[i] = ldin(src, i & 255, isf32);
    }
    if (t == 0) *flag = isf32;
  }
}

// ---------------------------------------------------------------------------
// R17/R19-verified FUSED q/v/k conv (byte-identical). Tm=256, Tco=16,
// 2 blocks/CU (validated optimum ~50us). q epilogue pre-scales by QSCALE.
// B via global_load_lds(16B).
// Attention coords (R2/R11-verified): slab=(b<<4)+(co>>4), m=(co&15)*64+(n>>4),
//   d=n&15;  q/k rows: (slab<<14)+((co&15)<<10)+n ;  v (V^T):
//   (slab<<14)+((n&15)<<10)+((co&15)<<6)+(n>>4)
// ---------------------------------------------------------------------------
__global__ __launch_bounds__(256, 2) void convqkv_kernel(
    const unsigned short* __restrict__ xbf,
    const unsigned short* __restrict__ wFq,  // 1 tap
    const unsigned short* __restrict__ wFv,  // 9 taps
    const unsigned short* __restrict__ wFk,  // 25 taps
    const float* __restrict__ bc,            // [3][256] q,v,k
    unsigned short* __restrict__ qOut,
    unsigned short* __restrict__ vOut,
    unsigned short* __restrict__ kOut) {
  constexpr int WC = 36;            // halo cols (32 + 2*2)
  constexpr int CELLS = 12 * WC;    // 12 halo rows = 432 cells
  constexpr int LOADS = CELLS * 4;  // 1728 halo dwordx4 loads
  __shared__ unsigned short Xs[CELLS * 40];  // halo [cell][32ci pad40] 34.6KB
  __shared__ unsigned short Bs[36 * 512];    // B [tap35+1][lane64][8]  36.9KB
  const int t    = threadIdx.x;
  const int bid  = blockIdx.x;
  const int cog0 = bid & 15;
  const int co0  = cog0 << 4;
  const int m0   = (bid >> 4) << 8;    // 256 positions (8 image rows)
  const int b    = m0 >> 10;
  const int n0   = m0 & 1023;
  const int r0   = n0 >> 5;
  const int wv   = t >> 6;
  const int lane = t & 63;
  const int l15  = lane & 15;
  const int quad = lane >> 4;

  floatx4 aq[4] = {}, av[4] = {}, ak[4] = {};

  for (int c8 = 0; c8 < 8; ++c8) {
    uint4 xreg[7];
#pragma unroll
    for (int rr = 0; rr < 7; ++rr) {
      const int id = rr * 256 + t;
      const int cell = id >> 2, part = id & 3;
      const int hr = cell / WC, wc = cell - hr * WC;
      const int xr = r0 + hr - 2, xc = wc - 2;
      const bool ok = (id < LOADS) && ((unsigned)xr < 32u) &&
                      ((unsigned)xc < 32u);
      const int cr = xr < 0 ? 0 : (xr > 31 ? 31 : xr);
      const int cc = xc < 0 ? 0 : (xc > 31 ? 31 : xc);
      uint4 v = *(const uint4*)&xbf[(((b * 32 + cr) * 32 + cc) << 8) +
                                    (c8 << 5) + (part << 3)];
      if (!ok) v = make_uint4(0, 0, 0, 0);
      xreg[rr] = v;
    }
    __syncthreads();
#pragma unroll
    for (int rr = 0; rr < 9; ++rr) {
      const int tap = (rr << 2) + wv;
      if (tap < 35) {
        const unsigned short* src;
        if (tap < 25) {
          src = &wFk[((((tap << 3) + c8) << 4) + cog0) * 512];
        } else if (tap < 34) {
          src = &wFv[(((((tap - 25) << 3) + c8) << 4) + cog0) * 512];
        } else {
          src = &wFq[((c8 << 4) + cog0) * 512];
        }
        __builtin_amdgcn_global_load_lds((g_u32*)(src + (lane << 3)),
                                         (l_u32*)&Bs[tap << 9], 16, 0, 0);
      }
    }
#pragma unroll
    for (int rr = 0; rr < 7; ++rr) {
      const int id = rr * 256 + t;
      if (id < LOADS)
        *(uint4*)&Xs[(id >> 2) * 40 + ((id & 3) << 3)] = xreg[rr];
    }
    __syncthreads();

#pragma unroll
    for (int tap = 0; tap < 25; ++tap) {
      const int kh = tap / 5, kw = tap % 5;
      const bool vv = (kh >= 1 && kh <= 3 && kw >= 1 && kw <= 3);
      short8 a[4];
#pragma unroll
      for (int rr2 = 0; rr2 < 2; ++rr2) {
#pragma unroll
        for (int ch = 0; ch < 2; ++ch) {
          const unsigned short* xs =
              &Xs[(((wv << 1) + rr2 + kh) * WC + (ch << 4) + l15 + kw) * 40 +
                  (quad << 3)];
          a[(rr2 << 1) + ch] = *(const short8*)xs;
        }
      }
      const short8 kb = *(const short8*)&Bs[(tap << 9) + (lane << 3)];
#pragma unroll
      for (int f = 0; f < 4; ++f)
        ak[f] = __builtin_amdgcn_mfma_f32_16x16x32_bf16(a[f], kb, ak[f],
                                                        0, 0, 0);
      if (vv) {
        const int vt = (kh - 1) * 3 + (kw - 1);
        const short8 vb = *(const short8*)&Bs[((25 + vt) << 9) + (lane << 3)];
#pragma unroll
        for (int f = 0; f < 4; ++f)
          av[f] = __builtin_amdgcn_mfma_f32_16x16x32_bf16(a[f], vb, av[f],
                                                          0, 0, 0);
      }
      if (tap == 12) {
        const short8 qb = *(const short8*)&Bs[(34 << 9) + (lane << 3)];
#pragma unroll
        for (int f = 0; f < 4; ++f)
          aq[f] = __builtin_amdgcn_mfma_f32_16x16x32_bf16(a[f], qb, aq[f],
                                                          0, 0, 0);
      }
    }
  }
#pragma unroll
  for (int rr2 = 0; rr2 < 2; ++rr2) {
#pragma unroll
    for (int ch = 0; ch < 2; ++ch) {
      const int f = (rr2 << 1) + ch;
      const int co = co0 + l15;
      const int slab = (b << 4) + (co >> 4);
      const int clo = co & 15;
      const int nb = n0 + (wv << 6) + (rr2 << 5) + (ch << 4) + (quad << 2);
      {
        const float bj = bc[co];
        floatx4 a = aq[f];
        ushort4 pk4;
        pk4.x = f2bf((a[0] + bj) * QSCALE);
        pk4.y = f2bf((a[1] + bj) * QSCALE);
        pk4.z = f2bf((a[2] + bj) * QSCALE);
        pk4.w = f2bf((a[3] + bj) * QSCALE);
        *(ushort4*)&qOut[(slab << 14) + (clo << 10) + nb] = pk4;
      }
      {
        const float bj = bc[512 + co];
        floatx4 a = ak[f];
        ushort4 pk4;
        pk4.x = f2bf(a[0] + bj); pk4.y = f2bf(a[1] + bj);
        pk4.z = f2bf(a[2] + bj); pk4.w = f2bf(a[3] + bj);
        *(ushort4*)&kOut[(slab << 14) + (clo << 10) + nb] = pk4;
      }
      {
        const float bj = bc[256 + co];
        floatx4 a = av[f];
        const int base = (slab << 14) + (clo << 6);
#pragma unroll
        for (int i = 0; i < 4; ++i) {
          const int n = nb + i;
          vOut[base + ((n & 15) << 10) + (n >> 4)] = f2bf(a[i] + bj);
        }
      }
    }
  }
}

// ---------------------------------------------------------------------------
// R17-verified MFMA attention (byte-identical): single-inst exp2, truncating
// bf16 P-store, ones-MFMA row sums, K/V from global, barrier-free, 10.2 KB.
// ---------------------------------------------------------------------------
__global__ __launch_bounds__(256, 4) void attn_mfma_kernel(
    const unsigned short* __restrict__ qg,
    const unsigned short* __restrict__ kg,
    const unsigned short* __restrict__ vg,
    unsigned short* __restrict__ out2) {
  __shared__ __align__(16) unsigned short Pb[4][32][40];  // per-wave P
  const int t    = threadIdx.x;
  const int w    = t >> 6;
  const int lane = t & 63;
  const int slab = blockIdx.x >> 3;
  const int rb   = blockIdx.x & 7;
  const int b = slab >> 4;
  const int h = slab & 15;
  const int l31  = lane & 31;
  const int hl   = lane >> 5;
  const int l15  = lane & 15;
  const int quad = lane >> 4;

  const unsigned short* Kb = kg + (slab << 14);
  const unsigned short* Vb = vg + (slab << 14);

  const int row0 = (rb << 7) + (w << 5);
  const short8 qa =
      *(const short8*)&qg[(slab << 14) + ((row0 + l31) << 4) + (hl << 3)];

  const short onebf = (short)0x3F80;  // bf16 1.0
  const short8 ones = {onebf, onebf, onebf, onebf, onebf, onebf, onebf, onebf};

  floatx4 acco[2] = {}, asum[2] = {};

  for (int kc = 0; kc < 1024; kc += 32) {
    const short8 kb = *(const short8*)&Kb[((kc + l31) << 4) + (hl << 3)];
    floatx16 s = {};
    s = __builtin_amdgcn_mfma_f32_32x32x16_bf16(qa, kb, s, 0, 0, 0);
#pragma unroll
    for (int r = 0; r < 16; ++r) {
      const float e = __builtin_amdgcn_exp2f(s[r]);  // scale pre-folded in Q
      const int row = (r & 3) + ((r >> 2) << 3) + (hl << 2);
      Pb[w][row][l31] = f2bf_trunc(e);
    }
    const short8 vb = *(const short8*)&Vb[(l15 << 10) + kc + (quad << 3)];
#pragma unroll
    for (int tt = 0; tt < 2; ++tt) {
      const short8 pa = *(const short8*)&Pb[w][(tt << 4) + l15][quad << 3];
      acco[tt] =
          __builtin_amdgcn_mfma_f32_16x16x32_bf16(pa, vb, acco[tt], 0, 0, 0);
      asum[tt] =
          __builtin_amdgcn_mfma_f32_16x16x32_bf16(pa, ones, asum[tt], 0, 0, 0);
    }
  }
#pragma unroll
  for (int tt = 0; tt < 2; ++tt) {
#pragma unroll
    for (int r = 0; r < 4; ++r) {
      const int nloc = (tt << 4) + (quad << 2) + r;
      const float val = acco[tt][r] / asum[tt][r];
      const int n = row0 + nloc;
      out2[(((b << 10) + n) << 8) + (h << 4) + l15] = f2bf(val);
    }
  }
}

// ---------------------------------------------------------------------------
// Final linear, MFMA bf16, with one-chunk-ahead B register prefetch.
// ---------------------------------------------------------------------------
__global__ __launch_bounds__(256) void linear_mfma_kernel(
    const unsigned short* __restrict__ inp,  // bf16 [8192][256]
    const unsigned short* __restrict__ wpF,  // fragment order
    void* __restrict__ out, const int* __restrict__ flag) {
  __shared__ unsigned short As[64 * 40];
  const int isf32 = *flag;
  const int t   = threadIdx.x;
  const int m0  = blockIdx.x << 6;
  const int co0 = blockIdx.y << 6;
  const int wv   = t >> 6;
  const int lane = t & 63;
  const int wm = (wv & 1) << 5;
  const int wn = (wv >> 1) << 5;
  const int l15  = lane & 15;
  const int quad = lane >> 4;
  const int cogb = (co0 >> 4) + (wn >> 4);
  const int rowS = t >> 2;
  const int partS = t & 3;

  floatx4 acc[2][2] = {};

  short8 cb0, cb1;
  {
    const unsigned short* wptr = &wpF[(cogb << 9) + (lane << 3)];
    cb0 = *(const short8*)wptr;
    cb1 = *(const short8*)(wptr + 512);
  }
  for (int c8 = 0; c8 < 8; ++c8) {
    const uint4 v = *(const uint4*)&inp[((m0 + rowS) << 8) + (c8 << 5) +
                                        (partS << 3)];
    short8 nb0 = {}, nb1 = {};
    if (c8 + 1 < 8) {
      const unsigned short* wptr =
          &wpF[((((c8 + 1) << 4) + cogb) << 9) + (lane << 3)];
      nb0 = *(const short8*)wptr;
      nb1 = *(const short8*)(wptr + 512);
    }
    __syncthreads();
    *(uint4*)&As[rowS * 40 + (partS << 3)] = v;
    __syncthreads();
    const unsigned short* xs = &As[(wm + l15) * 40 + (quad << 3)];
    const short8 afr0 = *(const short8*)xs;
    const short8 afr1 = *(const short8*)(xs + 16 * 40);
    acc[0][0] = __builtin_amdgcn_mfma_f32_16x16x32_bf16(afr0, cb0,
                                                        acc[0][0], 0, 0, 0);
    acc[0][1] = __builtin_amdgcn_mfma_f32_16x16x32_bf16(afr0, cb1,
                                                        acc[0][1], 0, 0, 0);
    acc[1][0] = __builtin_amdgcn_mfma_f32_16x16x32_bf16(afr1, cb0,
                                                        acc[1][0], 0, 0, 0);
    acc[1][1] = __builtin_amdgcn_mfma_f32_16x16x32_bf16(afr1, cb1,
                                                        acc[1][1], 0, 0, 0);
    cb0 = nb0; cb1 = nb1;
  }
#pragma unroll
  for (int mi = 0; mi < 2; ++mi) {
#pragma unroll
    for (int ni = 0; ni < 2; ++ni) {
      const int co = co0 + wn + (ni << 4) + l15;
      const int mb = m0 + wm + (mi << 4) + (quad << 2);
      floatx4 a = acc[mi][ni];
      if (!isf32) {
        unsigned short* o16 = (unsigned short*)out;
#pragma unroll
        for (int r = 0; r < 4; ++r) o16[(mb + r) * 256 + co] = f2bf(a[r]);
      } else {
        float* o32 = (float*)out;
#pragma unroll
        for (int r = 0; r < 4; ++r) o32[(mb + r) * 256 + co] = a[r];
      }
    }
  }
}

// ---------------------------------------------------------------------------
extern "C" void kernel_launch(void* const* d_in, const int* in_sizes, int n_in,
                              void* d_out, int out_size, void* d_ws,
                              size_t ws_size, hipStream_t stream) {
  const void* x  = d_in[0];
  const void* w3 = d_in[1];
  const void* b3 = d_in[2];
  const void* w5 = d_in[3];
  const void* b5 = d_in[4];
  const void* w7 = d_in[5];
  const void* b7 = d_in[6];
  const void* wp = d_in[7];

  char* p = (char*)d_ws;
  int* flag = (int*)p;                       p += 256;
  unsigned short* xbf = (unsigned short*)p;  p += 4u * 1024 * 1024;
  unsigned short* wF3 = (unsigned short*)p;  p += 131072;
  unsigned short* wF5 = (unsigned short*)p;  p += 1179648;
  unsigned short* wF7 = (unsigned short*)p;  p += 3276800;
  unsigned short* wpF = (unsigned short*)p;  p += 131072;
  float* bc = (float*)p;                     p += 4096;     // [3][256]
  unsigned short* qc  = (unsigned short*)p;  p += 4194304;  // bf16 QK rows
  unsigned short* kT  = (unsigned short*)p;  p += 4194304;  // bf16 QK rows
  unsigned short* vT  = (unsigned short*)p;  p += 4194304;  // bf16 V^T
  unsigned short* o2b = (unsigned short*)p;  p += 4194304;  // bf16 [8192][256]

  prep_kernel<<<1025, 256, 0, stream>>>(x, w3, b3, w5, b5, w7, b7, wp, xbf,
                                        wF3, wF5, wF7, wpF, bc, flag);

  convqkv_kernel<<<512, 256, 0, stream>>>(xbf, wF3, wF5, wF7, bc, qc, vT, kT);

  attn_mfma_kernel<<<1024, 256, 0, stream>>>(qc, kT, vT, o2b);

  dim3 lg(128, 4);
  linear_mfma_kernel<<<lg, 256, 0, stream>>>(o2b, wpF, d_out, flag);
}